// Round 5
// baseline (73.660 us; speedup 1.0000x reference)
//
#include <hip/hip_runtime.h>
#include <hip/hip_bf16.h>
#include <stdint.h>

// Full attention fwd: N=4, L=S=2048, H=8, D=64, fp32 in/out.
// Round 5: dual independent softmax streams per wave (A: KV tiles 0..31,
// B: 32..63, KVBLK=32) to break the per-iter dependency chain; phases batched
// A;B so the scheduler interleaves the two independent chains. No LDS, no
// barriers; fragment-major K/V in d_ws (prepass); 32x32x16 MFMA swapped
// QK^T/PV; in-register P via pack+permlane32_swap; exp2 domain; merged
// defer-max branch; streams merged in-register at epilogue.

typedef __bf16 bf16x8 __attribute__((ext_vector_type(8)));
typedef float  f32x16 __attribute__((ext_vector_type(16)));

#define N_ 4
#define L_ 2048
#define S_ 2048
#define H_ 8
#define D_ 64
#define NH 32
#define QBLK 128
#define NT32 64                          // 32-row KV tiles per plane
#define TILE32 4096                      // bf16 per tile: 8 sections x 512
#define PLANE_BF16 (NT32 * TILE32)       // 262144 bf16 = 512KB per (n,h)
#define SCALE_LOG2E 0.18033688011112042f // (1/sqrt(64)) * log2(e)

static __device__ __forceinline__ uint32_t pkbf(float lo, float hi) {
    uint16_t l = __builtin_bit_cast(uint16_t, (__bf16)lo);
    uint16_t h = __builtin_bit_cast(uint16_t, (__bf16)hi);
    return (uint32_t)l | ((uint32_t)h << 16);
}

static __device__ __forceinline__ float tmax16(const f32x16& s) {
    float a[8];
#pragma unroll
    for (int i = 0; i < 8; ++i) a[i] = fmaxf(s[i], s[i + 8]);
#pragma unroll
    for (int w = 4; w >= 1; w >>= 1)
#pragma unroll
        for (int i = 0; i < w; ++i) a[i] = fmaxf(a[i], a[i + w]);
    return a[0];
}

static __device__ __forceinline__ float tsum16(const f32x16& s) {
    float a[8];
#pragma unroll
    for (int i = 0; i < 8; ++i) a[i] = s[i] + s[i + 8];
#pragma unroll
    for (int w = 4; w >= 1; w >>= 1)
#pragma unroll
        for (int i = 0; i < w; ++i) a[i] += a[i + w];
    return a[0];
}

// pack 16 f32 P-values -> 2 bf16x8 B-fragments via permlane32_swap
static __device__ __forceinline__ void packP(const f32x16& s, bf16x8 (&pf)[2]) {
    uint32_t W[8];
#pragma unroll
    for (int i = 0; i < 8; ++i) W[i] = pkbf(s[2 * i], s[2 * i + 1]);
#pragma unroll
    for (int kt = 0; kt < 2; ++kt) {
        uint32_t a0 = W[4 * kt + 0], b0 = W[4 * kt + 2];
        uint32_t a1 = W[4 * kt + 1], b1 = W[4 * kt + 3];
        asm volatile("v_permlane32_swap_b32 %0, %1" : "+v"(a0), "+v"(b0));
        asm volatile("v_permlane32_swap_b32 %0, %1" : "+v"(a1), "+v"(b1));
        union { uint32_t u[4]; bf16x8 v; } pu;
        pu.u[0] = a0; pu.u[1] = a1; pu.u[2] = b0; pu.u[3] = b1;
        pf[kt] = pu.v;
    }
}

// ---- prepass K: fp32 [n][s][h][d] -> fragment-major bf16 (sections 0..3) ----
__global__ __launch_bounds__(256) void prep_k(const float* __restrict__ K,
                                              __bf16* __restrict__ F) {
    const int ch   = blockIdx.x * 256 + threadIdx.x;  // 524288 16B-chunks
    const int nh   = ch >> 14;            // 16384 chunks per plane
    const int r    = ch & 16383;
    const int t    = r >> 8;              // 32-row tile, 0..63
    const int rr   = r & 255;
    const int sl   = rr >> 3;             // s within tile, 0..31
    const int slot = rr & 7;              // d octet
    const int n = nh >> 3, h = nh & 7;
    const float* p = K + ((size_t)(n * 2048 + t * 32 + sl) * 8 + h) * 64 + slot * 8;
    float4 a = *(const float4*)p;
    float4 b = *(const float4*)(p + 4);
    bf16x8 v;
    v[0] = (__bf16)a.x; v[1] = (__bf16)a.y; v[2] = (__bf16)a.z; v[3] = (__bf16)a.w;
    v[4] = (__bf16)b.x; v[5] = (__bf16)b.y; v[6] = (__bf16)b.z; v[7] = (__bf16)b.w;
    const int ks = slot >> 1, hh = slot & 1;
    *(bf16x8*)(F + (size_t)nh * PLANE_BF16 + t * TILE32
                 + ks * 512 + (hh * 32 + sl) * 8) = v;
}

// ---- prepass V: fp32 [n][s][h][d] -> transposed fragment-major (sections 4..7) ----
__global__ __launch_bounds__(256) void prep_v(const float* __restrict__ V,
                                              __bf16* __restrict__ F) {
    __shared__ __align__(16) __bf16 T[64 * 64];
    const int tid = threadIdx.x;
    const int bid = blockIdx.x;          // nh*32 + 64-s-chunk
    const int nh  = bid >> 5;
    const int t0  = (bid & 31) * 2;      // first 32-row tile of this chunk
    const int n   = nh >> 3, h = nh & 7;
    const int s0  = (bid & 31) * 64;
#pragma unroll
    for (int it = 0; it < 16; ++it) {
        const int idx = it * 256 + tid;
        const int sl  = idx >> 6;
        const int d   = idx & 63;
        float v = V[(size_t)(n * 2048 + s0 + sl) * 512 + h * 64 + d];
        T[d * 64 + (((sl >> 3) ^ (d & 7)) * 8) + (sl & 7)] = (__bf16)v;
    }
    __syncthreads();
#pragma unroll
    for (int it = 0; it < 2; ++it) {
        const int idx = it * 256 + tid;   // 0..511
        const int d   = idx >> 3;
        const int sc  = idx & 7;          // s octet within 64
        bf16x8 v = *(const bf16x8*)&T[d * 64 + ((sc ^ (d & 7)) * 8)];
        const int dt = d >> 5, c = d & 31;
        const int tile = t0 + (sc >> 2), kt = (sc >> 1) & 1, hh = sc & 1;
        *(bf16x8*)(F + (size_t)nh * PLANE_BF16 + tile * TILE32
                     + (4 + dt * 2 + kt) * 512 + (hh * 32 + c) * 8) = v;
    }
}

// ---------------- main attention kernel (no LDS, no barriers) ----------------
__global__ __launch_bounds__(256, 2) void fattn(const float* __restrict__ Q,
                                                const __bf16* __restrict__ F,
                                                float* __restrict__ Out) {
    const int tid  = threadIdx.x;
    const int wave = tid >> 6;
    const int lane = tid & 63;
    const int hh   = lane >> 5;
    const int c    = lane & 31;

    int bid = blockIdx.x;
    bid = (bid & 7) * 64 + (bid >> 3);   // XCD swizzle (512 % 8 == 0 -> bijective)
    const int nh = bid >> 4;
    const int qt = bid & 15;
    const int n  = nh >> 3, hd = nh & 7;
    const int q0 = qt * QBLK;

    const float*  Qp = Q   + (size_t)n * 1048576 + hd * 64;
    float*        Op = Out + (size_t)n * 1048576 + hd * 64;
    const bf16x8* Tb = (const bf16x8*)(F + (size_t)nh * PLANE_BF16); // 512 chunks/tile

    // Q B-fragments (col = q = c, k = d = ks*16 + hh*8 + j), scaled
    bf16x8 qf[4];
    {
        const float* qp = Qp + (size_t)(q0 + wave * 32 + c) * 512;
#pragma unroll
        for (int ks = 0; ks < 4; ++ks) {
            float4 a = *(const float4*)(qp + ks * 16 + hh * 8);
            float4 b = *(const float4*)(qp + ks * 16 + hh * 8 + 4);
            bf16x8 v;
            v[0] = (__bf16)(a.x * SCALE_LOG2E); v[1] = (__bf16)(a.y * SCALE_LOG2E);
            v[2] = (__bf16)(a.z * SCALE_LOG2E); v[3] = (__bf16)(a.w * SCALE_LOG2E);
            v[4] = (__bf16)(b.x * SCALE_LOG2E); v[5] = (__bf16)(b.y * SCALE_LOG2E);
            v[6] = (__bf16)(b.z * SCALE_LOG2E); v[7] = (__bf16)(b.w * SCALE_LOG2E);
            qf[ks] = v;
        }
    }

    // dual-stream state
    float mA = -1e30f, lA = 0.f, mB = -1e30f, lB = 0.f;
    f32x16 oA0, oA1, oB0, oB1;
#pragma unroll
    for (int r = 0; r < 16; ++r) { oA0[r] = 0.f; oA1[r] = 0.f; oB0[r] = 0.f; oB1[r] = 0.f; }

    bf16x8 kA[4], vA[4], kB[4], vB[4];
#pragma unroll
    for (int f = 0; f < 4; ++f) {
        kA[f] = Tb[0 * 512 + f * 64 + lane];
        vA[f] = Tb[0 * 512 + 256 + f * 64 + lane];
        kB[f] = Tb[32 * 512 + f * 64 + lane];
        vB[f] = Tb[32 * 512 + 256 + f * 64 + lane];
    }

    for (int t = 0; t < 32; ++t) {
        const int tn = (t + 1 < 32) ? t + 1 : 31;   // clamped tail reload

        // ---- QK^T both streams (independent MFMA chains) ----
        f32x16 sA, sB;
#pragma unroll
        for (int r = 0; r < 16; ++r) { sA[r] = 0.f; sB[r] = 0.f; }
        __builtin_amdgcn_s_setprio(1);
#pragma unroll
        for (int ks = 0; ks < 4; ++ks) {
            sA = __builtin_amdgcn_mfma_f32_32x32x16_bf16(kA[ks], qf[ks], sA, 0, 0, 0);
            sB = __builtin_amdgcn_mfma_f32_32x32x16_bf16(kB[ks], qf[ks], sB, 0, 0, 0);
        }
        __builtin_amdgcn_s_setprio(0);

        // reload K fragments for next iter (consumed above)
#pragma unroll
        for (int f = 0; f < 4; ++f) {
            kA[f] = Tb[tn * 512 + f * 64 + lane];
            kB[f] = Tb[(tn + 32) * 512 + f * 64 + lane];
        }

        // ---- softmax: two independent chains, one merged rare branch ----
        float tmA = tmax16(sA), tmB = tmax16(sB);
        tmA = fmaxf(tmA, __shfl_xor(tmA, 32, 64));
        tmB = fmaxf(tmB, __shfl_xor(tmB, 32, 64));
        if (!__all((tmA <= mA + 8.0f) && (tmB <= mB + 8.0f))) {
            const float nmA = fmaxf(mA, tmA), nmB = fmaxf(mB, tmB);
            const float aA = __builtin_amdgcn_exp2f(mA - nmA);
            const float aB = __builtin_amdgcn_exp2f(mB - nmB);
            mA = nmA; mB = nmB; lA *= aA; lB *= aB;
#pragma unroll
            for (int r = 0; r < 16; ++r) {
                oA0[r] *= aA; oA1[r] *= aA; oB0[r] *= aB; oB1[r] *= aB;
            }
        }
#pragma unroll
        for (int r = 0; r < 16; ++r) {
            sA[r] = __builtin_amdgcn_exp2f(sA[r] - mA);
            sB[r] = __builtin_amdgcn_exp2f(sB[r] - mB);
        }
        lA += tsum16(sA);
        lB += tsum16(sB);

        bf16x8 pfA[2], pfB[2];
        packP(sA, pfA);
        packP(sB, pfB);

        // ---- PV both streams ----
        __builtin_amdgcn_s_setprio(1);
        oA0 = __builtin_amdgcn_mfma_f32_32x32x16_bf16(vA[0], pfA[0], oA0, 0, 0, 0);
        oB0 = __builtin_amdgcn_mfma_f32_32x32x16_bf16(vB[0], pfB[0], oB0, 0, 0, 0);
        oA0 = __builtin_amdgcn_mfma_f32_32x32x16_bf16(vA[1], pfA[1], oA0, 0, 0, 0);
        oB0 = __builtin_amdgcn_mfma_f32_32x32x16_bf16(vB[1], pfB[1], oB0, 0, 0, 0);
        oA1 = __builtin_amdgcn_mfma_f32_32x32x16_bf16(vA[2], pfA[0], oA1, 0, 0, 0);
        oB1 = __builtin_amdgcn_mfma_f32_32x32x16_bf16(vB[2], pfB[0], oB1, 0, 0, 0);
        oA1 = __builtin_amdgcn_mfma_f32_32x32x16_bf16(vA[3], pfA[1], oA1, 0, 0, 0);
        oB1 = __builtin_amdgcn_mfma_f32_32x32x16_bf16(vB[3], pfB[1], oB1, 0, 0, 0);
        __builtin_amdgcn_s_setprio(0);

        // reload V fragments for next iter (consumed above)
#pragma unroll
        for (int f = 0; f < 4; ++f) {
            vA[f] = Tb[tn * 512 + 256 + f * 64 + lane];
            vB[f] = Tb[(tn + 32) * 512 + 256 + f * 64 + lane];
        }
    }

    // ---- epilogue: finish per-stream l, merge streams, normalize, store ----
    lA += __shfl_xor(lA, 32, 64);
    lB += __shfl_xor(lB, 32, 64);
    const float m  = fmaxf(mA, mB);
    const float eA = __builtin_amdgcn_exp2f(mA - m);
    const float eB = __builtin_amdgcn_exp2f(mB - m);
    const float inv = 1.0f / (lA * eA + lB * eB);
    const float cA = eA * inv, cB = eB * inv;

    float* op = Op + (size_t)(q0 + wave * 32 + c) * 512;
#pragma unroll
    for (int rr = 0; rr < 4; ++rr) {
        float4 o0 = { oA0[4 * rr + 0] * cA + oB0[4 * rr + 0] * cB,
                      oA0[4 * rr + 1] * cA + oB0[4 * rr + 1] * cB,
                      oA0[4 * rr + 2] * cA + oB0[4 * rr + 2] * cB,
                      oA0[4 * rr + 3] * cA + oB0[4 * rr + 3] * cB };
        *(float4*)(op + rr * 8 + hh * 4) = o0;
        float4 o1 = { oA1[4 * rr + 0] * cA + oB1[4 * rr + 0] * cB,
                      oA1[4 * rr + 1] * cA + oB1[4 * rr + 1] * cB,
                      oA1[4 * rr + 2] * cA + oB1[4 * rr + 2] * cB,
                      oA1[4 * rr + 3] * cA + oB1[4 * rr + 3] * cB };
        *(float4*)(op + 32 + rr * 8 + hh * 4) = o1;
    }
}

extern "C" void kernel_launch(void* const* d_in, const int* in_sizes, int n_in,
                              void* d_out, int out_size, void* d_ws, size_t ws_size,
                              hipStream_t stream) {
    const float* Q = (const float*)d_in[0];
    const float* K = (const float*)d_in[1];
    const float* V = (const float*)d_in[2];
    float* Out = (float*)d_out;
    __bf16* F = (__bf16*)d_ws;   // 16 MB fragment-major K+V

    prep_k<<<dim3(2048), dim3(256), 0, stream>>>(K, F);
    prep_v<<<dim3(1024), dim3(256), 0, stream>>>(V, F);
    fattn <<<dim3(512),  dim3(256), 0, stream>>>(Q, F, Out);
}